// Round 2
// baseline (119.007 us; speedup 1.0000x reference)
//
#include <hip/hip_runtime.h>
#include <math.h>

// STFT -> mag/phase -> ISTFT collapses algebraically to an elementwise scale:
//   out[b,i] = input[b,i] * gain(i)
//   gain(i)  = (400/401) * sum_{k=0..3} hann800((n%200) + 200k)  [frame-clamped]
// with n = i+400, hann800(w) = 0.5 - 0.5*cos(2*pi*w/799).
// Proof sketch: mag*cos(atan2(si,sr)) == sr and mag*sin == si (identity, incl.
// the si==0 & sr<0 special case: cos(pi)=-1); the half-end-weighted trapezoidal
// iDFT kernel equals 400*delta[d mod 800] exactly (Dirichlet telescoping), so
// contrib = (400/401)*win*frame; overlap-add of the squared... no — of the
// window then scales each padded sample by the hann overlap sum; the
// [PAD:-PAD] crop keeps only samples where x_pad == input (reflect padding
// never reaches the output).
//
// Single fused kernel: gain computed inline (16 cosf/thread ~ 3 us of VALU,
// hidden under the 20 us HBM stream). Compulsory traffic: 61.44 MB read +
// 61.44 MB write = 123 MB -> ~19-20 us at 6.3-6.4 TB/s achievable.

#define T_OUT   480000
#define NBATCH  32
#define PADK    400
#define HOPK    200
#define NFRAMES 2401
#define GAIN_SCALE 0.9975062344139651f   // 400/401

__device__ __forceinline__ float hann800(int w) {
    // np.hanning(800)[w] = 0.5 - 0.5*cos(2*pi*w/799)
    const float c = 6.2831853071795864769f / 799.0f;
    return 0.5f - 0.5f * cosf(c * (float)w);
}

__device__ __forceinline__ float gain_at(int i) {
    int n = i + PADK;
    int r = n % HOPK;
    int q = n / HOPK;                     // frame index of the k=0 term
    float g = 0.0f;
#pragma unroll
    for (int k = 0; k < 4; ++k) {
        int t = q - k;                    // frame contributing window pos r+200k
        if (t >= 0 && t < NFRAMES)
            g += hann800(r + HOPK * k);
    }
    return g * GAIN_SCALE;
}

__global__ void stft_roundtrip_scale_kernel(const float4* __restrict__ in,
                                            float4* __restrict__ out) {
    int i4 = blockIdx.x * blockDim.x + threadIdx.x;   // float4 index within row
    if (i4 >= T_OUT / 4) return;
    size_t idx = (size_t)blockIdx.y * (T_OUT / 4) + i4;
    int i = i4 * 4;
    float4 x = in[idx];
    float4 o;
    o.x = x.x * gain_at(i + 0);
    o.y = x.y * gain_at(i + 1);
    o.z = x.z * gain_at(i + 2);
    o.w = x.w * gain_at(i + 3);
    out[idx] = o;
}

extern "C" void kernel_launch(void* const* d_in, const int* in_sizes, int n_in,
                              void* d_out, int out_size, void* d_ws, size_t ws_size,
                              hipStream_t stream) {
    (void)d_ws; (void)ws_size; (void)in_sizes; (void)n_in; (void)out_size;
    const float4* in = (const float4*)d_in[0];
    float4* out = (float4*)d_out;

    const int row4 = T_OUT / 4;                 // 120000 float4 per row
    dim3 block(256);
    dim3 grid((row4 + 255) / 256, NBATCH);      // (469, 32) = 15008 blocks

    stft_roundtrip_scale_kernel<<<grid, block, 0, stream>>>(in, out);
}

// Round 3
// 103.524 us; speedup vs baseline: 1.1496x; 1.1496x over previous
//
#include <hip/hip_runtime.h>
#include <math.h>

// STFT -> mag/phase -> ISTFT collapses algebraically to an elementwise scale:
//   out[b,i] = input[b,i] * gain(i)
//   gain(i)  = (400/401) * sum_{k in active(i)} hann800(r + 200k)
// with n = i+400, r = n%200, hann800(w) = 0.5 - 0.5*cos(2*pi*w/799).
// active(i): k=0..3, minus k=3 for i<200 (frame t would be -1), minus k=0 for
// i>=479800 (frame t would be 2401). Verified pass (absmax 0.0625) in R1/R2.
//
// R2 lesson: libm cosf (range reduction) made the kernel VALU-bound (VALUBusy
// ~120%, 43.5 us vs ~19.5 us memory floor). Fix: angle addition — the k-sum
// collapses to  base - 0.5*(cos(a)*SC - sin(a)*SS),  a = 2*pi*r/799, with
// SC/SS per-case constants computed on host in double and passed as args.
// One v_cos + one v_sin per element (__cosf/__sinf fast path, arg < 1.6 rad).

#define T_OUT   480000
#define NBATCH  32
#define GAIN_SCALE 0.9975062344139651f   // 400/401

struct GainConsts {
    float c4, s4;       // interior: sum_{k=0..3} cos/sin(theta_k)
    float c3, s3;       // i < 200:  sum_{k=0..2}
    float ce, se;       // i >= 479800: sum_{k=1..3}
};

__device__ __forceinline__ float gain_fast(int i, const GainConsts gc) {
    int n = i + 400;
    int r = n % 200;
    float C, S, base;
    if (i < 200)             { C = gc.c3; S = gc.s3; base = 1.5f; }
    else if (i >= 479800)    { C = gc.ce; S = gc.se; base = 1.5f; }
    else                     { C = gc.c4; S = gc.s4; base = 2.0f; }
    const float ang = 6.2831853071795864769f / 799.0f;   // 2*pi/799
    float a = (float)r * ang;                            // in [0, 1.58)
    float g = base - 0.5f * (__cosf(a) * C - __sinf(a) * S);
    return g * GAIN_SCALE;
}

__global__ void stft_roundtrip_scale_kernel(const float4* __restrict__ in,
                                            float4* __restrict__ out,
                                            const GainConsts gc) {
    int i4 = blockIdx.x * blockDim.x + threadIdx.x;   // float4 index within row
    if (i4 >= T_OUT / 4) return;
    size_t idx = (size_t)blockIdx.y * (T_OUT / 4) + i4;
    int i = i4 * 4;
    float4 x = in[idx];
    float4 o;
    o.x = x.x * gain_fast(i + 0, gc);
    o.y = x.y * gain_fast(i + 1, gc);
    o.z = x.z * gain_fast(i + 2, gc);
    o.w = x.w * gain_fast(i + 3, gc);
    out[idx] = o;
}

extern "C" void kernel_launch(void* const* d_in, const int* in_sizes, int n_in,
                              void* d_out, int out_size, void* d_ws, size_t ws_size,
                              hipStream_t stream) {
    (void)d_ws; (void)ws_size; (void)in_sizes; (void)n_in; (void)out_size;
    const float4* in = (const float4*)d_in[0];
    float4* out = (float4*)d_out;

    // theta_k = 2*pi*200*k/799; per-case cos/sin sums in double precision.
    GainConsts gc;
    {
        const double th = 2.0 * M_PI * 200.0 / 799.0;
        double c[4], s[4];
        for (int k = 0; k < 4; ++k) { c[k] = cos(th * k); s[k] = sin(th * k); }
        gc.c4 = (float)(c[0] + c[1] + c[2] + c[3]);
        gc.s4 = (float)(s[0] + s[1] + s[2] + s[3]);
        gc.c3 = (float)(c[0] + c[1] + c[2]);
        gc.s3 = (float)(s[0] + s[1] + s[2]);
        gc.ce = (float)(c[1] + c[2] + c[3]);
        gc.se = (float)(s[1] + s[2] + s[3]);
    }

    const int row4 = T_OUT / 4;                 // 120000 float4 per row
    dim3 block(256);
    dim3 grid((row4 + 255) / 256, NBATCH);      // (469, 32) = 15008 blocks

    stft_roundtrip_scale_kernel<<<grid, block, 0, stream>>>(in, out, gc);
}